// Round 4
// baseline (734.028 us; speedup 1.0000x reference)
//
#include <hip/hip_runtime.h>

typedef __bf16 bf16x8 __attribute__((ext_vector_type(8)));
typedef float  f32x4  __attribute__((ext_vector_type(4)));

#define TOKS 4096
#define DIM  1024
#define NEXP 8
#define NF   4096
#define CAP  4096   // per-expert pair capacity
#define BM 128
#define BN 128
#define BK 64

typedef __attribute__((address_space(3))) unsigned int as3_u32;
typedef __attribute__((address_space(1))) unsigned int as1_u32;
// async global->LDS, 16B per lane; LDS dest = wave-uniform base + lane*16
__device__ __forceinline__ void gl16(const unsigned short* g, unsigned short* l) {
  __builtin_amdgcn_global_load_lds((as1_u32*)(unsigned long long)g, (as3_u32*)l, 16, 0, 0);
}
// drain prefetch + barrier, placed AFTER compute (T3-min schedule)
#define DRAIN_BAR() do { \
  asm volatile("s_waitcnt vmcnt(0)" ::: "memory"); \
  __builtin_amdgcn_s_barrier(); \
} while (0)

__device__ __forceinline__ unsigned short f2bf(float f) {
  unsigned int u = __float_as_uint(f);
  u += 0x7FFFu + ((u >> 16) & 1u);           // round-to-nearest-even
  return (unsigned short)(u >> 16);
}
// fallback-kernel swizzle
__device__ __forceinline__ int swzo(int major) {
  return ((major & 7) ^ ((major >> 3) & 7)) << 3;
}
// XOR 16B-chunk index with row&7; arg/result in elements (8 bf16 chunks)
__device__ __forceinline__ int swz8(int row, int chunk) {
  return (chunk ^ (row & 7)) << 3;
}

// ---------------- routing ----------------
__global__ void moe_route(const float* __restrict__ x, const float* __restrict__ Wg,
                          int* __restrict__ pairCnt, int* __restrict__ pairIdx,
                          float* __restrict__ pairWgt, float* __restrict__ auxSum)
{
  int lane = threadIdx.x & 63;
  int tok  = blockIdx.x * 4 + (threadIdx.x >> 6);
  const float* xr = x + (size_t)tok * DIM;
  float acc[8];
  #pragma unroll
  for (int e = 0; e < 8; ++e) acc[e] = 0.f;
  #pragma unroll
  for (int i = 0; i < 16; ++i) {
    int d = i * 64 + lane;
    float xv = xr[d];
    const float4* wr = (const float4*)(Wg + d * 8);
    float4 wa = wr[0], wb = wr[1];
    acc[0] += xv * wa.x; acc[1] += xv * wa.y; acc[2] += xv * wa.z; acc[3] += xv * wa.w;
    acc[4] += xv * wb.x; acc[5] += xv * wb.y; acc[6] += xv * wb.z; acc[7] += xv * wb.w;
  }
  #pragma unroll
  for (int e = 0; e < 8; ++e) {
    float v = acc[e];
    #pragma unroll
    for (int off = 32; off; off >>= 1) v += __shfl_xor(v, off);
    acc[e] = v;
  }
  if (lane == 0) {
    int e1 = 0; float l1 = acc[0];
    #pragma unroll
    for (int e = 1; e < 8; ++e) if (acc[e] > l1) { l1 = acc[e]; e1 = e; }
    int e2 = -1; float l2 = -3.4e38f;
    #pragma unroll
    for (int e = 0; e < 8; ++e) if (e != e1 && acc[e] > l2) { l2 = acc[e]; e2 = e; }
    float r  = expf(l2 - l1);
    float w1 = 1.f / (1.f + r);
    float w2 = r / (1.f + r);
    int s1 = atomicAdd(&pairCnt[e1], 1);
    pairIdx[e1 * CAP + s1] = tok * 2;     pairWgt[e1 * CAP + s1] = w1;
    int s2 = atomicAdd(&pairCnt[e2], 1);
    pairIdx[e2 * CAP + s2] = tok * 2 + 1; pairWgt[e2 * CAP + s2] = w2;
    float m = 0.f;
    #pragma unroll
    for (int e = 0; e < 8; ++e) m += acc[e];
    m *= 0.125f;
    float v = 0.f;
    #pragma unroll
    for (int e = 0; e < 8; ++e) { float dd = acc[e] - m; v += dd * dd; }
    atomicAdd(auxSum, v * (1.f / 7.f));
  }
}

__global__ void moe_aux_final(const float* __restrict__ auxSum, float* __restrict__ outScalar) {
  *outScalar = auxSum[0] * (1.f / (float)TOKS);
}

// ---------------- x: fp32 -> bf16 ----------------
__global__ __launch_bounds__(256) void cvt_x(const float* __restrict__ in,
                                             unsigned short* __restrict__ o)
{
  int i = (blockIdx.x * 256 + threadIdx.x) * 16;
  const float4* s = (const float4*)(in + i);
  float4 a = s[0], b = s[1], c = s[2], d = s[3];
  union { unsigned short u[8]; uint4 q; } p0, p1;
  p0.u[0]=f2bf(a.x); p0.u[1]=f2bf(a.y); p0.u[2]=f2bf(a.z); p0.u[3]=f2bf(a.w);
  p0.u[4]=f2bf(b.x); p0.u[5]=f2bf(b.y); p0.u[6]=f2bf(b.z); p0.u[7]=f2bf(b.w);
  p1.u[0]=f2bf(c.x); p1.u[1]=f2bf(c.y); p1.u[2]=f2bf(c.z); p1.u[3]=f2bf(c.w);
  p1.u[4]=f2bf(d.x); p1.u[5]=f2bf(d.y); p1.u[6]=f2bf(d.z); p1.u[7]=f2bf(d.w);
  *(uint4*)(o + i)     = p0.q;
  *(uint4*)(o + i + 8) = p1.q;
}

// ---------------- weight prep: fp32 [E][R][C] -> bf16 [E][C][R] ----------------
__global__ __launch_bounds__(256) void cvt_transpose(
    const float* __restrict__ in, unsigned short* __restrict__ outp, int R, int C)
{
  __shared__ unsigned short tile[64 * 72];
  int e  = blockIdx.z;
  int r0 = blockIdx.x * 64, c0 = blockIdx.y * 64;
  const float*    ine  = in   + (size_t)e * R * C;
  unsigned short* oute = outp + (size_t)e * R * C;
  int t = threadIdx.x;
  int r = t >> 2, cs = (t & 3) * 16;
  const float4* src = (const float4*)(ine + (size_t)(r0 + r) * C + c0 + cs);
  #pragma unroll
  for (int j = 0; j < 4; ++j) {
    float4 v = src[j];
    tile[(cs + j * 4 + 0) * 72 + r] = f2bf(v.x);
    tile[(cs + j * 4 + 1) * 72 + r] = f2bf(v.y);
    tile[(cs + j * 4 + 2) * 72 + r] = f2bf(v.z);
    tile[(cs + j * 4 + 3) * 72 + r] = f2bf(v.w);
  }
  __syncthreads();
  int c = t >> 2, rs = (t & 3) * 16;
  uint4 o0 = *(const uint4*)&tile[c * 72 + rs];
  uint4 o1 = *(const uint4*)&tile[c * 72 + rs + 8];
  unsigned short* dst = oute + (size_t)(c0 + c) * R + r0 + rs;
  *(uint4*)dst       = o0;
  *(uint4*)(dst + 8) = o1;
}

// ---------------- FFN1 compute helper: one K-half (K=32) of MFMA ----------------
__device__ __forceinline__ void ffn1_mma(
    const unsigned short* B1b, const unsigned short* B3b,
    bf16x8 a0, bf16x8 a1, int kc, int wn, int lane,
    f32x4 acc1[2][4], f32x4 acc2[2][4])
{
  #pragma unroll
  for (int ni = 0; ni < 4; ++ni) {
    int f = wn + ni * 16 + (lane & 15);
    bf16x8 b1 = *(const bf16x8*)(&B1b[f * BK + swz8(f, kc)]);
    bf16x8 b3 = *(const bf16x8*)(&B3b[f * BK + swz8(f, kc)]);
    acc1[0][ni] = __builtin_amdgcn_mfma_f32_16x16x32_bf16(a0, b1, acc1[0][ni], 0, 0, 0);
    acc2[0][ni] = __builtin_amdgcn_mfma_f32_16x16x32_bf16(a0, b3, acc2[0][ni], 0, 0, 0);
    acc1[1][ni] = __builtin_amdgcn_mfma_f32_16x16x32_bf16(a1, b1, acc1[1][ni], 0, 0, 0);
    acc2[1][ni] = __builtin_amdgcn_mfma_f32_16x16x32_bf16(a1, b3, acc2[1][ni], 0, 0, 0);
  }
}

// ---------------- FFN1 (pipelined): h = silu(x@W1) * (x@W3) ----------------
// B1/B3 double-buffered in LDS via global_load_lds prefetch-1; A-fragments in
// registers loaded directly from xbf (L2/L3-resident), prefetch-1.
// Single barrier per K-step, placed AFTER compute: reads of buf[cur^1]
// completed before the previous iteration's barrier, so this iteration's
// prefetch into buf[cur^1] cannot race them.
__global__ __launch_bounds__(512, 4) void moe_ffn1_p(
    const unsigned short* __restrict__ xbf, const unsigned short* __restrict__ W1T,
    const unsigned short* __restrict__ W3T,
    const int* __restrict__ pairCnt, const int* __restrict__ pairIdx,
    unsigned short* __restrict__ hbuf)
{
  // bid bits: [0:3)=n_low(XCD), [3:8)=m, [8:10)=n_high, [10:13)=e
  int bid = blockIdx.x;
  int m_t = (bid >> 3) & 31;
  int n_t = (bid & 7) | (((bid >> 8) & 3) << 3);
  int e   = bid >> 10;
  int cnt = pairCnt[e];
  int m0  = m_t * BM;
  if (m0 >= cnt) return;
  int n0  = n_t * BN;
  __shared__ __attribute__((aligned(16))) unsigned short B1s[2][BN * BK];
  __shared__ __attribute__((aligned(16))) unsigned short B3s[2][BN * BK];
  __shared__ int rowPid[BM];
  int tid = threadIdx.x, lane = tid & 63, wid = tid >> 6;
  if (tid < BM) {
    int gi = m0 + tid;
    rowPid[tid] = (gi < cnt) ? pairIdx[e * CAP + gi] : -1;
  }
  const unsigned short* W1e = W1T + (size_t)e * NF * DIM + (size_t)n0 * DIM;
  const unsigned short* W3e = W3T + (size_t)e * NF * DIM + (size_t)n0 * DIM;
  f32x4 zero = {0.f, 0.f, 0.f, 0.f};
  f32x4 acc1[2][4], acc2[2][4];
  #pragma unroll
  for (int mi = 0; mi < 2; ++mi)
    #pragma unroll
    for (int ni = 0; ni < 4; ++ni) { acc1[mi][ni] = zero; acc2[mi][ni] = zero; }
  int wm = (wid >> 1) * 32, wn = (wid & 1) * 64;
  __syncthreads();   // rowPid visible

  // B staging sources (wave stages B rows wid*16 .. wid*16+15)
  int r0a = wid * 16 + (lane >> 3), r1a = r0a + 8;
  int ch0 = ((lane & 7) ^ (r0a & 7)) * 8;
  int ch1 = ((lane & 7) ^ (r1a & 7)) * 8;
  const unsigned short* gB10 = W1e + (size_t)r0a * DIM + ch0;
  const unsigned short* gB11 = W1e + (size_t)r1a * DIM + ch1;
  const unsigned short* gB30 = W3e + (size_t)r0a * DIM + ch0;
  const unsigned short* gB31 = W3e + (size_t)r1a * DIM + ch1;
  unsigned short* l1b0 = &B1s[0][(wid * 16) * BK];
  unsigned short* l1b1 = &B1s[1][(wid * 16) * BK];
  unsigned short* l3b0 = &B3s[0][(wid * 16) * BK];
  unsigned short* l3b1 = &B3s[1][(wid * 16) * BK];

  // A sources: per-lane direct (consumption rows wm+(lane&15), wm+16+(lane&15))
  int pm0 = rowPid[wm + (lane & 15)];
  int pm1 = rowPid[wm + 16 + (lane & 15)];
  const unsigned short* pA0 = xbf + (size_t)((pm0 >= 0) ? (pm0 >> 1) : 0) * DIM + (lane >> 4) * 8;
  const unsigned short* pA1 = xbf + (size_t)((pm1 >= 0) ? (pm1 >> 1) : 0) * DIM + (lane >> 4) * 8;

  // prologue: stage tile 0 into buf0, load A regs for kt=0
  gl16(gB10, l1b0); gl16(gB11, l1b0 + 8 * BK);
  gl16(gB30, l3b0); gl16(gB31, l3b0 + 8 * BK);
  bf16x8 aA00 = *(const bf16x8*)(pA0);
  bf16x8 aA01 = *(const bf16x8*)(pA0 + 32);
  bf16x8 aA10 = *(const bf16x8*)(pA1);
  bf16x8 aA11 = *(const bf16x8*)(pA1 + 32);
  DRAIN_BAR();

  for (int kt = 0; kt < DIM; kt += 2 * BK) {
    // ---- body A: prefetch kt+BK into buf1 + A regs; compute buf0 @ kt ----
    int kN = kt + BK;   // always < DIM (DIM/BK even)
    gl16(gB10 + kN, l1b1); gl16(gB11 + kN, l1b1 + 8 * BK);
    gl16(gB30 + kN, l3b1); gl16(gB31 + kN, l3b1 + 8 * BK);
    bf16x8 aB00 = *(const bf16x8*)(pA0 + kN);
    bf16x8 aB01 = *(const bf16x8*)(pA0 + kN + 32);
    bf16x8 aB10 = *(const bf16x8*)(pA1 + kN);
    bf16x8 aB11 = *(const bf16x8*)(pA1 + kN + 32);
    ffn1_mma(B1s[0], B3s[0], aA00, aA10, (lane >> 4),     wn, lane, acc1, acc2);
    ffn1_mma(B1s[0], B3s[0], aA01, aA11, 4 + (lane >> 4), wn, lane, acc1, acc2);
    DRAIN_BAR();
    // ---- body B: prefetch kt+2BK into buf0 + A regs; compute buf1 @ kt+BK ----
    int kP = kt + 2 * BK;
    if (kP < DIM) {
      gl16(gB10 + kP, l1b0); gl16(gB11 + kP, l1b0 + 8 * BK);
      gl16(gB30 + kP, l3b0); gl16(gB31 + kP, l3b0 + 8 * BK);
      aA00 = *(const bf16x8*)(pA0 + kP);
      aA01 = *(const bf16x8*)(pA0 + kP + 32);
      aA10 = *(const bf16x8*)(pA1 + kP);
      aA11 = *(const bf16x8*)(pA1 + kP + 32);
    }
    ffn1_mma(B1s[1], B3s[1], aB00, aB10, (lane >> 4),     wn, lane, acc1, acc2);
    ffn1_mma(B1s[1], B3s[1], aB01, aB11, 4 + (lane >> 4), wn, lane, acc1, acc2);
    DRAIN_BAR();
  }
  // epilogue: h = silu(a) * g -> bf16
  #pragma unroll
  for (int mi = 0; mi < 2; ++mi) {
    #pragma unroll
    for (int r = 0; r < 4; ++r) {
      int row = wm + mi * 16 + ((lane >> 4) << 2) + r;
      int pid = rowPid[row];
      if (pid < 0) continue;
      size_t hb = (size_t)pid * NF + n0 + wn + (lane & 15);
      #pragma unroll
      for (int ni = 0; ni < 4; ++ni) {
        float a = acc1[mi][ni][r];
        float g = acc2[mi][ni][r];
        float s = 1.f / (1.f + __expf(-a));
        hbuf[hb + ni * 16] = f2bf(a * s * g);
      }
    }
  }
}

// ---------------- FFN2 compute helper ----------------
__device__ __forceinline__ void ffn2_mma(
    const unsigned short* Ab, const unsigned short* Bb,
    int wm, int wn, int lane, f32x4 acc[2][4])
{
  #pragma unroll
  for (int ks = 0; ks < 2; ++ks) {
    int kc = ks * 4 + (lane >> 4);
    bf16x8 af[2];
    #pragma unroll
    for (int mi = 0; mi < 2; ++mi) {
      int row = wm + mi * 16 + (lane & 15);
      af[mi] = *(const bf16x8*)(&Ab[row * BK + swz8(row, kc)]);
    }
    #pragma unroll
    for (int ni = 0; ni < 4; ++ni) {
      int dc = wn + ni * 16 + (lane & 15);
      bf16x8 b = *(const bf16x8*)(&Bb[dc * BK + swz8(dc, kc)]);
      #pragma unroll
      for (int mi = 0; mi < 2; ++mi)
        acc[mi][ni] = __builtin_amdgcn_mfma_f32_16x16x32_bf16(af[mi], b, acc[mi][ni], 0, 0, 0);
    }
  }
}

// ---------------- FFN2 (pipelined): out[tok] += w * (h @ W2) ----------------
__global__ __launch_bounds__(512, 4) void moe_ffn2_p(
    const unsigned short* __restrict__ hbuf, const unsigned short* __restrict__ W2T,
    const int* __restrict__ pairCnt, const int* __restrict__ pairIdx,
    const float* __restrict__ pairWgt, float* __restrict__ out)
{
  // bid bits: [0:3)=n(XCD), [3:8)=m, [8:11)=e
  int bid = blockIdx.x;
  int n_t = bid & 7;
  int m_t = (bid >> 3) & 31;
  int e   = bid >> 8;
  int cnt = pairCnt[e];
  int m0  = m_t * BM;
  if (m0 >= cnt) return;
  int n0  = n_t * BN;
  __shared__ __attribute__((aligned(16))) unsigned short As[2][BM * BK];
  __shared__ __attribute__((aligned(16))) unsigned short Bs[2][BN * BK];
  __shared__ int   rowPid[BM];
  __shared__ float rowW[BM];
  int tid = threadIdx.x, lane = tid & 63, wid = tid >> 6;
  if (tid < BM) {
    int gi = m0 + tid;
    if (gi < cnt) { rowPid[tid] = pairIdx[e * CAP + gi]; rowW[tid] = pairWgt[e * CAP + gi]; }
    else          { rowPid[tid] = -1;                    rowW[tid] = 0.f; }
  }
  const unsigned short* W2e = W2T + (size_t)e * DIM * NF + (size_t)n0 * NF;
  f32x4 zero = {0.f, 0.f, 0.f, 0.f};
  f32x4 acc[2][4];
  #pragma unroll
  for (int mi = 0; mi < 2; ++mi)
    #pragma unroll
    for (int ni = 0; ni < 4; ++ni) acc[mi][ni] = zero;
  int wm = (wid >> 1) * 32, wn = (wid & 1) * 64;
  __syncthreads();

  int r0a = wid * 16 + (lane >> 3), r1a = r0a + 8;
  int p0 = rowPid[r0a], p1 = rowPid[r1a];
  size_t h0 = (size_t)((p0 >= 0) ? p0 : 0);
  size_t h1 = (size_t)((p1 >= 0) ? p1 : 0);
  int ch0 = ((lane & 7) ^ (r0a & 7)) * 8;
  int ch1 = ((lane & 7) ^ (r1a & 7)) * 8;
  const unsigned short* gA0 = hbuf + h0 * NF + ch0;
  const unsigned short* gA1 = hbuf + h1 * NF + ch1;
  const unsigned short* gB0 = W2e + (size_t)r0a * NF + ch0;
  const unsigned short* gB1 = W2e + (size_t)r1a * NF + ch1;
  unsigned short* lab0 = &As[0][(wid * 16) * BK];
  unsigned short* lab1 = &As[1][(wid * 16) * BK];
  unsigned short* lbb0 = &Bs[0][(wid * 16) * BK];
  unsigned short* lbb1 = &Bs[1][(wid * 16) * BK];

  // prologue
  gl16(gA0, lab0); gl16(gA1, lab0 + 8 * BK);
  gl16(gB0, lbb0); gl16(gB1, lbb0 + 8 * BK);
  DRAIN_BAR();

  for (int kt = 0; kt < NF; kt += 2 * BK) {
    int kN = kt + BK;   // always < NF
    gl16(gA0 + kN, lab1); gl16(gA1 + kN, lab1 + 8 * BK);
    gl16(gB0 + kN, lbb1); gl16(gB1 + kN, lbb1 + 8 * BK);
    ffn2_mma(As[0], Bs[0], wm, wn, lane, acc);
    DRAIN_BAR();
    int kP = kt + 2 * BK;
    if (kP < NF) {
      gl16(gA0 + kP, lab0); gl16(gA1 + kP, lab0 + 8 * BK);
      gl16(gB0 + kP, lbb0); gl16(gB1 + kP, lbb0 + 8 * BK);
    }
    ffn2_mma(As[1], Bs[1], wm, wn, lane, acc);
    DRAIN_BAR();
  }
  #pragma unroll
  for (int mi = 0; mi < 2; ++mi) {
    #pragma unroll
    for (int r = 0; r < 4; ++r) {
      int row = wm + mi * 16 + ((lane >> 4) << 2) + r;
      int pid = rowPid[row];
      if (pid < 0) continue;
      float w = rowW[row];
      float* op = out + (size_t)(pid >> 1) * DIM + n0 + wn + (lane & 15);
      #pragma unroll
      for (int ni = 0; ni < 4; ++ni)
        atomicAdd(op + ni * 16, w * acc[mi][ni][r]);
    }
  }
}

// ================= fallback (fp32 weights in-kernel, small ws) =================
__global__ __launch_bounds__(512) void moe_ffn1(
    const float* __restrict__ x, const float* __restrict__ W1, const float* __restrict__ W3,
    const int* __restrict__ pairCnt, const int* __restrict__ pairIdx,
    unsigned short* __restrict__ hbuf)
{
  int e   = blockIdx.z;
  int cnt = pairCnt[e];
  int m0  = blockIdx.x * BM;
  if (m0 >= cnt) return;
  int n0  = blockIdx.y * BN;
  __shared__ __attribute__((aligned(16))) unsigned short As[BM * BK];
  __shared__ __attribute__((aligned(16))) unsigned short B1s[BN * BK];
  __shared__ __attribute__((aligned(16))) unsigned short B3s[BN * BK];
  __shared__ int rowPid[BM];
  int tid = threadIdx.x;
  if (tid < BM) {
    int gi = m0 + tid;
    rowPid[tid] = (gi < cnt) ? pairIdx[e * CAP + gi] : -1;
  }
  const float* W1e = W1 + (size_t)e * DIM * NF;
  const float* W3e = W3 + (size_t)e * DIM * NF;
  f32x4 zero = {0.f, 0.f, 0.f, 0.f};
  f32x4 acc1[2][4], acc2[2][4];
  #pragma unroll
  for (int mi = 0; mi < 2; ++mi)
    #pragma unroll
    for (int ni = 0; ni < 4; ++ni) { acc1[mi][ni] = zero; acc2[mi][ni] = zero; }
  int lane = tid & 63, wid = tid >> 6;
  int wm = (wid >> 1) * 32, wn = (wid & 1) * 64;

  for (int kt = 0; kt < DIM; kt += BK) {
    __syncthreads();
    #pragma unroll
    for (int it = 0; it < 4; ++it) {
      int row = it * 32 + (tid >> 4);
      int dq  = tid & 15;
      int pid = rowPid[row];
      int tk  = (pid >= 0) ? (pid >> 1) : 0;
      float4 v = *(const float4*)(x + (size_t)tk * DIM + kt + dq * 4);
      ushort4 b; b.x = f2bf(v.x); b.y = f2bf(v.y); b.z = f2bf(v.z); b.w = f2bf(v.w);
      *(ushort4*)(&As[row * BK + ((dq * 4) ^ swzo(row))]) = b;
    }
    #pragma unroll
    for (int it = 0; it < 4; ++it) {
      int d  = it * 16 + (tid >> 5);
      int fq = tid & 31;
      size_t go = (size_t)(kt + d) * NF + n0 + fq * 4;
      float4 v1 = *(const float4*)(W1e + go);
      float4 v3 = *(const float4*)(W3e + go);
      const float* p1 = (const float*)&v1;
      const float* p3 = (const float*)&v3;
      #pragma unroll
      for (int i = 0; i < 4; ++i) {
        int f   = fq * 4 + i;
        int idx = f * BK + (d ^ swzo(f));
        B1s[idx] = f2bf(p1[i]);
        B3s[idx] = f2bf(p3[i]);
      }
    }
    __syncthreads();
    #pragma unroll
    for (int ks = 0; ks < 2; ++ks) {
      int kb = ks * 32 + ((lane >> 4) << 3);
      bf16x8 af[2];
      #pragma unroll
      for (int mi = 0; mi < 2; ++mi) {
        int row = wm + mi * 16 + (lane & 15);
        af[mi] = *(const bf16x8*)(&As[row * BK + (kb ^ swzo(row))]);
      }
      #pragma unroll
      for (int ni = 0; ni < 4; ++ni) {
        int f = wn + ni * 16 + (lane & 15);
        bf16x8 b1 = *(const bf16x8*)(&B1s[f * BK + (kb ^ swzo(f))]);
        bf16x8 b3 = *(const bf16x8*)(&B3s[f * BK + (kb ^ swzo(f))]);
        #pragma unroll
        for (int mi = 0; mi < 2; ++mi) {
          acc1[mi][ni] = __builtin_amdgcn_mfma_f32_16x16x32_bf16(af[mi], b1, acc1[mi][ni], 0, 0, 0);
          acc2[mi][ni] = __builtin_amdgcn_mfma_f32_16x16x32_bf16(af[mi], b3, acc2[mi][ni], 0, 0, 0);
        }
      }
    }
  }
  #pragma unroll
  for (int mi = 0; mi < 2; ++mi) {
    #pragma unroll
    for (int r = 0; r < 4; ++r) {
      int row = wm + mi * 16 + ((lane >> 4) << 2) + r;
      int pid = rowPid[row];
      if (pid < 0) continue;
      size_t hb = (size_t)pid * NF + n0 + wn + (lane & 15);
      #pragma unroll
      for (int ni = 0; ni < 4; ++ni) {
        float a = acc1[mi][ni][r];
        float g = acc2[mi][ni][r];
        float s = 1.f / (1.f + __expf(-a));
        hbuf[hb + ni * 16] = f2bf(a * s * g);
      }
    }
  }
}

__global__ __launch_bounds__(512) void moe_ffn2(
    const unsigned short* __restrict__ hbuf, const float* __restrict__ W2,
    const int* __restrict__ pairCnt, const int* __restrict__ pairIdx,
    const float* __restrict__ pairWgt, float* __restrict__ out)
{
  int e   = blockIdx.z;
  int cnt = pairCnt[e];
  int m0  = blockIdx.x * BM;
  if (m0 >= cnt) return;
  int n0  = blockIdx.y * BN;
  __shared__ __attribute__((aligned(16))) unsigned short As[BM * BK];
  __shared__ __attribute__((aligned(16))) unsigned short Bs[BN * BK];
  __shared__ int   rowPid[BM];
  __shared__ float rowW[BM];
  int tid = threadIdx.x;
  if (tid < BM) {
    int gi = m0 + tid;
    if (gi < cnt) { rowPid[tid] = pairIdx[e * CAP + gi]; rowW[tid] = pairWgt[e * CAP + gi]; }
    else          { rowPid[tid] = -1;                    rowW[tid] = 0.f; }
  }
  const float* W2e = W2 + (size_t)e * NF * DIM;
  f32x4 zero = {0.f, 0.f, 0.f, 0.f};
  f32x4 acc[2][4];
  #pragma unroll
  for (int mi = 0; mi < 2; ++mi)
    #pragma unroll
    for (int ni = 0; ni < 4; ++ni) acc[mi][ni] = zero;
  int lane = tid & 63, wid = tid >> 6;
  int wm = (wid >> 1) * 32, wn = (wid & 1) * 64;

  for (int kt = 0; kt < NF; kt += BK) {
    __syncthreads();
    #pragma unroll
    for (int it = 0; it < 2; ++it) {
      int row = it * 64 + (tid >> 3);
      int c8  = tid & 7;
      int pid = rowPid[row];
      int pr  = (pid >= 0) ? pid : 0;
      uint4 v = *(const uint4*)(hbuf + (size_t)pr * NF + kt + c8 * 8);
      *(uint4*)(&As[row * BK + ((c8 * 8) ^ swzo(row))]) = v;
    }
    #pragma unroll
    for (int it = 0; it < 4; ++it) {
      int fk = it * 16 + (tid >> 5);
      int dq = tid & 31;
      float4 v = *(const float4*)(W2e + (size_t)(kt + fk) * DIM + n0 + dq * 4);
      const float* p = (const float*)&v;
      #pragma unroll
      for (int i = 0; i < 4; ++i) {
        int dc = dq * 4 + i;
        Bs[dc * BK + (fk ^ swzo(dc))] = f2bf(p[i]);
      }
    }
    __syncthreads();
    #pragma unroll
    for (int ks = 0; ks < 2; ++ks) {
      int kb = ks * 32 + ((lane >> 4) << 3);
      bf16x8 af[2];
      #pragma unroll
      for (int mi = 0; mi < 2; ++mi) {
        int row = wm + mi * 16 + (lane & 15);
        af[mi] = *(const bf16x8*)(&As[row * BK + (kb ^ swzo(row))]);
      }
      #pragma unroll
      for (int ni = 0; ni < 4; ++ni) {
        int dc = wn + ni * 16 + (lane & 15);
        bf16x8 b = *(const bf16x8*)(&Bs[dc * BK + (kb ^ swzo(dc))]);
        #pragma unroll
        for (int mi = 0; mi < 2; ++mi)
          acc[mi][ni] = __builtin_amdgcn_mfma_f32_16x16x32_bf16(af[mi], b, acc[mi][ni], 0, 0, 0);
      }
    }
  }
  #pragma unroll
  for (int mi = 0; mi < 2; ++mi) {
    #pragma unroll
    for (int r = 0; r < 4; ++r) {
      int row = wm + mi * 16 + ((lane >> 4) << 2) + r;
      int pid = rowPid[row];
      if (pid < 0) continue;
      float w = rowW[row];
      float* op = out + (size_t)(pid >> 1) * DIM + n0 + wn + (lane & 15);
      #pragma unroll
      for (int ni = 0; ni < 4; ++ni)
        atomicAdd(op + ni * 16, w * acc[mi][ni][r]);
    }
  }
}

extern "C" void kernel_launch(void* const* d_in, const int* in_sizes, int n_in,
                              void* d_out, int out_size, void* d_ws, size_t ws_size,
                              hipStream_t stream)
{
  const float* x  = (const float*)d_in[0];
  const float* Wg = (const float*)d_in[1];
  const float* W1 = (const float*)d_in[2];
  const float* W2 = (const float*)d_in[3];
  const float* W3 = (const float*)d_in[4];
  float* out = (float*)d_out;
  char*  ws  = (char*)d_ws;
  int*   pairCnt = (int*)ws;
  float* auxSum  = (float*)(ws + 64);
  int*   pairIdx = (int*)(ws + 4096);
  float* pairWgt = (float*)(ws + 262144);
  // fast-path layout (from 1 MiB): xbf 8M, hbuf 64M, W1T 64M, W3T 64M, W2T 64M
  unsigned short* xbf  = (unsigned short*)(ws + ((size_t)1 << 20));
  unsigned short* hbuf = (unsigned short*)(ws + ((size_t)9 << 20));
  unsigned short* W1T  = (unsigned short*)(ws + ((size_t)73 << 20));
  unsigned short* W3T  = (unsigned short*)(ws + ((size_t)137 << 20));
  unsigned short* W2T  = (unsigned short*)(ws + ((size_t)201 << 20));
  const size_t WS_NEED = (size_t)265 << 20;

  hipMemsetAsync(ws, 0, 128, stream);
  hipMemsetAsync(d_out, 0, (size_t)out_size * sizeof(float), stream);
  moe_route<<<TOKS / 4, 256, 0, stream>>>(x, Wg, pairCnt, pairIdx, pairWgt, auxSum);
  moe_aux_final<<<1, 1, 0, stream>>>(auxSum, out + (out_size - 1));

  if (ws_size >= WS_NEED) {
    cvt_x<<<TOKS * DIM / (256 * 16), 256, 0, stream>>>(x, xbf);
    cvt_transpose<<<dim3(DIM / 64, NF / 64, NEXP), 256, 0, stream>>>(W1, W1T, DIM, NF);
    cvt_transpose<<<dim3(DIM / 64, NF / 64, NEXP), 256, 0, stream>>>(W3, W3T, DIM, NF);
    cvt_transpose<<<dim3(NF / 64, DIM / 64, NEXP), 256, 0, stream>>>(W2, W2T, NF, DIM);
    moe_ffn1_p<<<(TOKS / BM) * (NF / BN) * NEXP, 512, 0, stream>>>(xbf, W1T, W3T, pairCnt, pairIdx, hbuf);
    moe_ffn2_p<<<(TOKS / BM) * (DIM / BN) * NEXP, 512, 0, stream>>>(hbuf, W2T, pairCnt, pairIdx, pairWgt, out);
  } else {
    moe_ffn1<<<dim3(TOKS / BM, NF / BN, NEXP), 512, 0, stream>>>(x, W1, W3, pairCnt, pairIdx, hbuf);
    moe_ffn2<<<dim3(TOKS / BM, DIM / BN, NEXP), 512, 0, stream>>>(hbuf, W2, pairCnt, pairIdx, pairWgt, out);
  }
}

// Round 5
// 546.077 us; speedup vs baseline: 1.3442x; 1.3442x over previous
//
#include <hip/hip_runtime.h>

typedef __bf16 bf16x8 __attribute__((ext_vector_type(8)));
typedef float  f32x4  __attribute__((ext_vector_type(4)));

#define TOKS 4096
#define DIM  1024
#define NEXP 8
#define NF   4096
#define CAP  4096   // per-expert pair capacity
#define BM 128
#define BN 128
#define BK 64

typedef __attribute__((address_space(3))) unsigned int as3_u32;
typedef __attribute__((address_space(1))) unsigned int as1_u32;
// async global->LDS, 16B per lane; LDS dest = wave-uniform base + lane*16
__device__ __forceinline__ void gl16(const unsigned short* g, unsigned short* l) {
  __builtin_amdgcn_global_load_lds((as1_u32*)(unsigned long long)g, (as3_u32*)l, 16, 0, 0);
}

__device__ __forceinline__ unsigned short f2bf(float f) {
  unsigned int u = __float_as_uint(f);
  u += 0x7FFFu + ((u >> 16) & 1u);           // round-to-nearest-even
  return (unsigned short)(u >> 16);
}
// fallback-kernel swizzle
__device__ __forceinline__ int swzo(int major) {
  return ((major & 7) ^ ((major >> 3) & 7)) << 3;
}
// XOR 16B-chunk index with row&7; arg/result in elements (8 bf16 chunks)
__device__ __forceinline__ int swz8(int row, int chunk) {
  return (chunk ^ (row & 7)) << 3;
}

// ---------------- routing ----------------
__global__ void moe_route(const float* __restrict__ x, const float* __restrict__ Wg,
                          int* __restrict__ pairCnt, int* __restrict__ pairIdx,
                          float* __restrict__ pairWgt, float* __restrict__ auxSum)
{
  int lane = threadIdx.x & 63;
  int tok  = blockIdx.x * 4 + (threadIdx.x >> 6);
  const float* xr = x + (size_t)tok * DIM;
  float acc[8];
  #pragma unroll
  for (int e = 0; e < 8; ++e) acc[e] = 0.f;
  #pragma unroll
  for (int i = 0; i < 16; ++i) {
    int d = i * 64 + lane;
    float xv = xr[d];
    const float4* wr = (const float4*)(Wg + d * 8);
    float4 wa = wr[0], wb = wr[1];
    acc[0] += xv * wa.x; acc[1] += xv * wa.y; acc[2] += xv * wa.z; acc[3] += xv * wa.w;
    acc[4] += xv * wb.x; acc[5] += xv * wb.y; acc[6] += xv * wb.z; acc[7] += xv * wb.w;
  }
  #pragma unroll
  for (int e = 0; e < 8; ++e) {
    float v = acc[e];
    #pragma unroll
    for (int off = 32; off; off >>= 1) v += __shfl_xor(v, off);
    acc[e] = v;
  }
  if (lane == 0) {
    int e1 = 0; float l1 = acc[0];
    #pragma unroll
    for (int e = 1; e < 8; ++e) if (acc[e] > l1) { l1 = acc[e]; e1 = e; }
    int e2 = -1; float l2 = -3.4e38f;
    #pragma unroll
    for (int e = 0; e < 8; ++e) if (e != e1 && acc[e] > l2) { l2 = acc[e]; e2 = e; }
    float r  = expf(l2 - l1);
    float w1 = 1.f / (1.f + r);
    float w2 = r / (1.f + r);
    int s1 = atomicAdd(&pairCnt[e1], 1);
    pairIdx[e1 * CAP + s1] = tok * 2;     pairWgt[e1 * CAP + s1] = w1;
    int s2 = atomicAdd(&pairCnt[e2], 1);
    pairIdx[e2 * CAP + s2] = tok * 2 + 1; pairWgt[e2 * CAP + s2] = w2;
    float m = 0.f;
    #pragma unroll
    for (int e = 0; e < 8; ++e) m += acc[e];
    m *= 0.125f;
    float v = 0.f;
    #pragma unroll
    for (int e = 0; e < 8; ++e) { float dd = acc[e] - m; v += dd * dd; }
    atomicAdd(auxSum, v * (1.f / 7.f));
  }
}

__global__ void moe_aux_final(const float* __restrict__ auxSum, float* __restrict__ outScalar) {
  *outScalar = auxSum[0] * (1.f / (float)TOKS);
}

// ---------------- x: fp32 -> bf16 ----------------
__global__ __launch_bounds__(256) void cvt_x(const float* __restrict__ in,
                                             unsigned short* __restrict__ o)
{
  int i = (blockIdx.x * 256 + threadIdx.x) * 16;
  const float4* s = (const float4*)(in + i);
  float4 a = s[0], b = s[1], c = s[2], d = s[3];
  union { unsigned short u[8]; uint4 q; } p0, p1;
  p0.u[0]=f2bf(a.x); p0.u[1]=f2bf(a.y); p0.u[2]=f2bf(a.z); p0.u[3]=f2bf(a.w);
  p0.u[4]=f2bf(b.x); p0.u[5]=f2bf(b.y); p0.u[6]=f2bf(b.z); p0.u[7]=f2bf(b.w);
  p1.u[0]=f2bf(c.x); p1.u[1]=f2bf(c.y); p1.u[2]=f2bf(c.z); p1.u[3]=f2bf(c.w);
  p1.u[4]=f2bf(d.x); p1.u[5]=f2bf(d.y); p1.u[6]=f2bf(d.z); p1.u[7]=f2bf(d.w);
  *(uint4*)(o + i)     = p0.q;
  *(uint4*)(o + i + 8) = p1.q;
}

// ---------------- weight prep: W2 fp32 [E][R][C] -> bf16 [E][C][R] ----------------
__global__ __launch_bounds__(256) void cvt_transpose(
    const float* __restrict__ in, unsigned short* __restrict__ outp, int R, int C)
{
  __shared__ unsigned short tile[64 * 72];
  int e  = blockIdx.z;
  int r0 = blockIdx.x * 64, c0 = blockIdx.y * 64;
  const float*    ine  = in   + (size_t)e * R * C;
  unsigned short* oute = outp + (size_t)e * R * C;
  int t = threadIdx.x;
  int r = t >> 2, cs = (t & 3) * 16;
  const float4* src = (const float4*)(ine + (size_t)(r0 + r) * C + c0 + cs);
  #pragma unroll
  for (int j = 0; j < 4; ++j) {
    float4 v = src[j];
    tile[(cs + j * 4 + 0) * 72 + r] = f2bf(v.x);
    tile[(cs + j * 4 + 1) * 72 + r] = f2bf(v.y);
    tile[(cs + j * 4 + 2) * 72 + r] = f2bf(v.z);
    tile[(cs + j * 4 + 3) * 72 + r] = f2bf(v.w);
  }
  __syncthreads();
  int c = t >> 2, rs = (t & 3) * 16;
  uint4 o0 = *(const uint4*)&tile[c * 72 + rs];
  uint4 o1 = *(const uint4*)&tile[c * 72 + rs + 8];
  unsigned short* dst = oute + (size_t)(c0 + c) * R + r0 + rs;
  *(uint4*)dst       = o0;
  *(uint4*)(dst + 8) = o1;
}

// ---------------- weight prep: W1,W3 fp32 [E][D][F] -> interleaved bf16 W13T ----------------
// W13T[e] has 2*NF rows of length DIM: row b*32 + w (w<16)  = W1 col b*16+w (transposed)
//                                      row b*32 + 16 + w    = W3 col b*16+w
__global__ __launch_bounds__(256) void cvt_w13(
    const float* __restrict__ W1, const float* __restrict__ W3,
    unsigned short* __restrict__ outp)
{
  __shared__ unsigned short t1[64 * 72];
  __shared__ unsigned short t3[64 * 72];
  int e  = blockIdx.z;
  int r0 = blockIdx.x * 64, c0 = blockIdx.y * 64;   // r0: D offset, c0: F offset
  const float* in1 = W1 + (size_t)e * DIM * NF;
  const float* in3 = W3 + (size_t)e * DIM * NF;
  unsigned short* oute = outp + (size_t)e * (2 * NF) * DIM;
  int t = threadIdx.x;
  int r = t >> 2, cs = (t & 3) * 16;
  const float4* s1 = (const float4*)(in1 + (size_t)(r0 + r) * NF + c0 + cs);
  const float4* s3 = (const float4*)(in3 + (size_t)(r0 + r) * NF + c0 + cs);
  #pragma unroll
  for (int j = 0; j < 4; ++j) {
    float4 v1 = s1[j];
    float4 v3 = s3[j];
    int cb = cs + j * 4;
    t1[(cb + 0) * 72 + r] = f2bf(v1.x);
    t1[(cb + 1) * 72 + r] = f2bf(v1.y);
    t1[(cb + 2) * 72 + r] = f2bf(v1.z);
    t1[(cb + 3) * 72 + r] = f2bf(v1.w);
    t3[(cb + 0) * 72 + r] = f2bf(v3.x);
    t3[(cb + 1) * 72 + r] = f2bf(v3.y);
    t3[(cb + 2) * 72 + r] = f2bf(v3.z);
    t3[(cb + 3) * 72 + r] = f2bf(v3.w);
  }
  __syncthreads();
  int c = t >> 2, rs = (t & 3) * 16;               // c: local f (0..63), rs: local d chunk
  int drow = c0 * 2 + (c >> 4) * 32 + (c & 15);    // interleaved dest row for W1
  uint4 a0 = *(const uint4*)&t1[c * 72 + rs];
  uint4 a1 = *(const uint4*)&t1[c * 72 + rs + 8];
  uint4 b0 = *(const uint4*)&t3[c * 72 + rs];
  uint4 b1 = *(const uint4*)&t3[c * 72 + rs + 8];
  unsigned short* d1 = oute + (size_t)drow * DIM + r0 + rs;
  unsigned short* d3 = d1 + (size_t)16 * DIM;
  *(uint4*)d1       = a0;
  *(uint4*)(d1 + 8) = a1;
  *(uint4*)d3       = b0;
  *(uint4*)(d3 + 8) = b1;
}

// ---------------- FFN1 (interleaved single-B GEMM): h = silu(x@W1) * (x@W3) ----------------
// B = W13T rows [n_t*128 .. +128): ni even fragments = W1 part (a), ni odd = W3 part (g),
// same f and same lane -> per-thread silu combine, no cross-lane.
__global__ __launch_bounds__(512) void moe_ffn1_i(
    const unsigned short* __restrict__ xbf, const unsigned short* __restrict__ W13T,
    const int* __restrict__ pairCnt, const int* __restrict__ pairIdx,
    unsigned short* __restrict__ hbuf)
{
  // bid bits: [0:3)=n_low(XCD), [3:8)=m, [8:11)=n_high, [11:14)=e
  int bid = blockIdx.x;
  int m_t = (bid >> 3) & 31;
  int n_t = (bid & 7) | (((bid >> 8) & 7) << 3);   // 0..63
  int e   = bid >> 11;
  int cnt = pairCnt[e];
  int m0  = m_t * BM;
  if (m0 >= cnt) return;
  int n0f = n_t * 64;                               // F offset of this block's output
  __shared__ __attribute__((aligned(16))) unsigned short As[BM * BK];
  __shared__ __attribute__((aligned(16))) unsigned short Bs[BN * BK];
  __shared__ int rowPid[BM];
  int tid = threadIdx.x, lane = tid & 63, wid = tid >> 6;
  if (tid < BM) {
    int gi = m0 + tid;
    rowPid[tid] = (gi < cnt) ? pairIdx[e * CAP + gi] : -1;
  }
  const unsigned short* W13e = W13T + (size_t)e * (2 * NF) * DIM + (size_t)n_t * 128 * DIM;
  f32x4 zero = {0.f, 0.f, 0.f, 0.f};
  f32x4 acc[2][4];
  #pragma unroll
  for (int mi = 0; mi < 2; ++mi)
    #pragma unroll
    for (int ni = 0; ni < 4; ++ni) acc[mi][ni] = zero;
  int wm = (wid >> 1) * 32, wn = (wid & 1) * 64;
  __syncthreads();   // rowPid visible

  // staging sources: wave covers rows wid*16 .. wid*16+15 of A and B tiles
  int r0a = wid * 16 + (lane >> 3), r1a = r0a + 8;
  int p0 = rowPid[r0a], p1 = rowPid[r1a];
  size_t tk0 = (size_t)((p0 >= 0) ? (p0 >> 1) : 0);
  size_t tk1 = (size_t)((p1 >= 0) ? (p1 >> 1) : 0);
  int ch0 = ((lane & 7) ^ (r0a & 7)) * 8;
  int ch1 = ((lane & 7) ^ (r1a & 7)) * 8;
  const unsigned short* gA0 = xbf + tk0 * DIM + ch0;
  const unsigned short* gA1 = xbf + tk1 * DIM + ch1;
  const unsigned short* gB0 = W13e + (size_t)r0a * DIM + ch0;
  const unsigned short* gB1 = W13e + (size_t)r1a * DIM + ch1;
  unsigned short* lA0 = &As[(wid * 16) * BK];
  unsigned short* lA1 = &As[(wid * 16 + 8) * BK];
  unsigned short* lB0 = &Bs[(wid * 16) * BK];
  unsigned short* lB1 = &Bs[(wid * 16 + 8) * BK];

  for (int kt = 0; kt < DIM; kt += BK) {
    gl16(gA0 + kt, lA0); gl16(gA1 + kt, lA1);
    gl16(gB0 + kt, lB0); gl16(gB1 + kt, lB1);
    __syncthreads();
    #pragma unroll
    for (int ks = 0; ks < 2; ++ks) {
      int kc = ks * 4 + (lane >> 4);   // 16B chunk along K
      bf16x8 af[2];
      #pragma unroll
      for (int mi = 0; mi < 2; ++mi) {
        int row = wm + mi * 16 + (lane & 15);
        af[mi] = *(const bf16x8*)(&As[row * BK + swz8(row, kc)]);
      }
      #pragma unroll
      for (int ni = 0; ni < 4; ++ni) {
        int br = wn + ni * 16 + (lane & 15);
        bf16x8 b = *(const bf16x8*)(&Bs[br * BK + swz8(br, kc)]);
        #pragma unroll
        for (int mi = 0; mi < 2; ++mi)
          acc[mi][ni] = __builtin_amdgcn_mfma_f32_16x16x32_bf16(af[mi], b, acc[mi][ni], 0, 0, 0);
      }
    }
    __syncthreads();
  }
  // epilogue: ni even = a (W1 part), ni odd = g (W3 part), same f & lane
  #pragma unroll
  for (int mi = 0; mi < 2; ++mi) {
    #pragma unroll
    for (int r = 0; r < 4; ++r) {
      int row = wm + mi * 16 + ((lane >> 4) << 2) + r;
      int pid = rowPid[row];
      if (pid < 0) continue;
      size_t hb = (size_t)pid * NF + n0f + (wn >> 1) + (lane & 15);
      #pragma unroll
      for (int fg = 0; fg < 2; ++fg) {
        float a = acc[mi][fg * 2 + 0][r];
        float g = acc[mi][fg * 2 + 1][r];
        float s = 1.f / (1.f + __expf(-a));
        hbuf[hb + fg * 16] = f2bf(a * s * g);
      }
    }
  }
}

// ---------------- FFN2 (global_load_lds staging): out[tok] += w * (h @ W2) ----------------
__global__ __launch_bounds__(512) void moe_ffn2_g(
    const unsigned short* __restrict__ hbuf, const unsigned short* __restrict__ W2T,
    const int* __restrict__ pairCnt, const int* __restrict__ pairIdx,
    const float* __restrict__ pairWgt, float* __restrict__ out)
{
  // bid bits: [0:3)=n(XCD), [3:8)=m, [8:11)=e
  int bid = blockIdx.x;
  int n_t = bid & 7;
  int m_t = (bid >> 3) & 31;
  int e   = bid >> 8;
  int cnt = pairCnt[e];
  int m0  = m_t * BM;
  if (m0 >= cnt) return;
  int n0  = n_t * BN;
  __shared__ __attribute__((aligned(16))) unsigned short As[BM * BK];
  __shared__ __attribute__((aligned(16))) unsigned short Bs[BN * BK];
  __shared__ int   rowPid[BM];
  __shared__ float rowW[BM];
  int tid = threadIdx.x, lane = tid & 63, wid = tid >> 6;
  if (tid < BM) {
    int gi = m0 + tid;
    if (gi < cnt) { rowPid[tid] = pairIdx[e * CAP + gi]; rowW[tid] = pairWgt[e * CAP + gi]; }
    else          { rowPid[tid] = -1;                    rowW[tid] = 0.f; }
  }
  const unsigned short* W2e = W2T + (size_t)e * DIM * NF + (size_t)n0 * NF;
  f32x4 zero = {0.f, 0.f, 0.f, 0.f};
  f32x4 acc[2][4];
  #pragma unroll
  for (int mi = 0; mi < 2; ++mi)
    #pragma unroll
    for (int ni = 0; ni < 4; ++ni) acc[mi][ni] = zero;
  int wm = (wid >> 1) * 32, wn = (wid & 1) * 64;
  __syncthreads();

  int r0a = wid * 16 + (lane >> 3), r1a = r0a + 8;
  int p0 = rowPid[r0a], p1 = rowPid[r1a];
  size_t h0 = (size_t)((p0 >= 0) ? p0 : 0);
  size_t h1 = (size_t)((p1 >= 0) ? p1 : 0);
  int ch0 = ((lane & 7) ^ (r0a & 7)) * 8;
  int ch1 = ((lane & 7) ^ (r1a & 7)) * 8;
  const unsigned short* gA0 = hbuf + h0 * NF + ch0;
  const unsigned short* gA1 = hbuf + h1 * NF + ch1;
  const unsigned short* gB0 = W2e + (size_t)r0a * NF + ch0;
  const unsigned short* gB1 = W2e + (size_t)r1a * NF + ch1;
  unsigned short* lA0 = &As[(wid * 16) * BK];
  unsigned short* lA1 = &As[(wid * 16 + 8) * BK];
  unsigned short* lB0 = &Bs[(wid * 16) * BK];
  unsigned short* lB1 = &Bs[(wid * 16 + 8) * BK];

  for (int kt = 0; kt < NF; kt += BK) {
    gl16(gA0 + kt, lA0); gl16(gA1 + kt, lA1);
    gl16(gB0 + kt, lB0); gl16(gB1 + kt, lB1);
    __syncthreads();
    #pragma unroll
    for (int ks = 0; ks < 2; ++ks) {
      int kc = ks * 4 + (lane >> 4);
      bf16x8 af[2];
      #pragma unroll
      for (int mi = 0; mi < 2; ++mi) {
        int row = wm + mi * 16 + (lane & 15);
        af[mi] = *(const bf16x8*)(&As[row * BK + swz8(row, kc)]);
      }
      #pragma unroll
      for (int ni = 0; ni < 4; ++ni) {
        int dc = wn + ni * 16 + (lane & 15);
        bf16x8 b = *(const bf16x8*)(&Bs[dc * BK + swz8(dc, kc)]);
        #pragma unroll
        for (int mi = 0; mi < 2; ++mi)
          acc[mi][ni] = __builtin_amdgcn_mfma_f32_16x16x32_bf16(af[mi], b, acc[mi][ni], 0, 0, 0);
      }
    }
    __syncthreads();
  }
  #pragma unroll
  for (int mi = 0; mi < 2; ++mi) {
    #pragma unroll
    for (int r = 0; r < 4; ++r) {
      int row = wm + mi * 16 + ((lane >> 4) << 2) + r;
      int pid = rowPid[row];
      if (pid < 0) continue;
      float w = rowW[row];
      float* op = out + (size_t)(pid >> 1) * DIM + n0 + wn + (lane & 15);
      #pragma unroll
      for (int ni = 0; ni < 4; ++ni)
        atomicAdd(op + ni * 16, w * acc[mi][ni][r]);
    }
  }
}

// ================= fallback (fp32 weights in-kernel, small ws) =================
__global__ __launch_bounds__(512) void moe_ffn1(
    const float* __restrict__ x, const float* __restrict__ W1, const float* __restrict__ W3,
    const int* __restrict__ pairCnt, const int* __restrict__ pairIdx,
    unsigned short* __restrict__ hbuf)
{
  int e   = blockIdx.z;
  int cnt = pairCnt[e];
  int m0  = blockIdx.x * BM;
  if (m0 >= cnt) return;
  int n0  = blockIdx.y * BN;
  __shared__ __attribute__((aligned(16))) unsigned short As[BM * BK];
  __shared__ __attribute__((aligned(16))) unsigned short B1s[BN * BK];
  __shared__ __attribute__((aligned(16))) unsigned short B3s[BN * BK];
  __shared__ int rowPid[BM];
  int tid = threadIdx.x;
  if (tid < BM) {
    int gi = m0 + tid;
    rowPid[tid] = (gi < cnt) ? pairIdx[e * CAP + gi] : -1;
  }
  const float* W1e = W1 + (size_t)e * DIM * NF;
  const float* W3e = W3 + (size_t)e * DIM * NF;
  f32x4 zero = {0.f, 0.f, 0.f, 0.f};
  f32x4 acc1[2][4], acc2[2][4];
  #pragma unroll
  for (int mi = 0; mi < 2; ++mi)
    #pragma unroll
    for (int ni = 0; ni < 4; ++ni) { acc1[mi][ni] = zero; acc2[mi][ni] = zero; }
  int lane = tid & 63, wid = tid >> 6;
  int wm = (wid >> 1) * 32, wn = (wid & 1) * 64;

  for (int kt = 0; kt < DIM; kt += BK) {
    __syncthreads();
    #pragma unroll
    for (int it = 0; it < 4; ++it) {
      int row = it * 32 + (tid >> 4);
      int dq  = tid & 15;
      int pid = rowPid[row];
      int tk  = (pid >= 0) ? (pid >> 1) : 0;
      float4 v = *(const float4*)(x + (size_t)tk * DIM + kt + dq * 4);
      ushort4 b; b.x = f2bf(v.x); b.y = f2bf(v.y); b.z = f2bf(v.z); b.w = f2bf(v.w);
      *(ushort4*)(&As[row * BK + ((dq * 4) ^ swzo(row))]) = b;
    }
    #pragma unroll
    for (int it = 0; it < 4; ++it) {
      int d  = it * 16 + (tid >> 5);
      int fq = tid & 31;
      size_t go = (size_t)(kt + d) * NF + n0 + fq * 4;
      float4 v1 = *(const float4*)(W1e + go);
      float4 v3 = *(const float4*)(W3e + go);
      const float* p1 = (const float*)&v1;
      const float* p3 = (const float*)&v3;
      #pragma unroll
      for (int i = 0; i < 4; ++i) {
        int f   = fq * 4 + i;
        int idx = f * BK + (d ^ swzo(f));
        B1s[idx] = f2bf(p1[i]);
        B3s[idx] = f2bf(p3[i]);
      }
    }
    __syncthreads();
    #pragma unroll
    for (int ks = 0; ks < 2; ++ks) {
      int kb = ks * 32 + ((lane >> 4) << 3);
      bf16x8 af[2];
      #pragma unroll
      for (int mi = 0; mi < 2; ++mi) {
        int row = wm + mi * 16 + (lane & 15);
        af[mi] = *(const bf16x8*)(&As[row * BK + (kb ^ swzo(row))]);
      }
      #pragma unroll
      for (int ni = 0; ni < 4; ++ni) {
        int f = wn + ni * 16 + (lane & 15);
        bf16x8 b1 = *(const bf16x8*)(&B1s[f * BK + (kb ^ swzo(f))]);
        bf16x8 b3 = *(const bf16x8*)(&B3s[f * BK + (kb ^ swzo(f))]);
        #pragma unroll
        for (int mi = 0; mi < 2; ++mi) {
          acc1[mi][ni] = __builtin_amdgcn_mfma_f32_16x16x32_bf16(af[mi], b1, acc1[mi][ni], 0, 0, 0);
          acc2[mi][ni] = __builtin_amdgcn_mfma_f32_16x16x32_bf16(af[mi], b3, acc2[mi][ni], 0, 0, 0);
        }
      }
    }
  }
  #pragma unroll
  for (int mi = 0; mi < 2; ++mi) {
    #pragma unroll
    for (int r = 0; r < 4; ++r) {
      int row = wm + mi * 16 + ((lane >> 4) << 2) + r;
      int pid = rowPid[row];
      if (pid < 0) continue;
      size_t hb = (size_t)pid * NF + n0 + wn + (lane & 15);
      #pragma unroll
      for (int ni = 0; ni < 4; ++ni) {
        float a = acc1[mi][ni][r];
        float g = acc2[mi][ni][r];
        float s = 1.f / (1.f + __expf(-a));
        hbuf[hb + ni * 16] = f2bf(a * s * g);
      }
    }
  }
}

__global__ __launch_bounds__(512) void moe_ffn2(
    const unsigned short* __restrict__ hbuf, const float* __restrict__ W2,
    const int* __restrict__ pairCnt, const int* __restrict__ pairIdx,
    const float* __restrict__ pairWgt, float* __restrict__ out)
{
  int e   = blockIdx.z;
  int cnt = pairCnt[e];
  int m0  = blockIdx.x * BM;
  if (m0 >= cnt) return;
  int n0  = blockIdx.y * BN;
  __shared__ __attribute__((aligned(16))) unsigned short As[BM * BK];
  __shared__ __attribute__((aligned(16))) unsigned short Bs[BN * BK];
  __shared__ int   rowPid[BM];
  __shared__ float rowW[BM];
  int tid = threadIdx.x;
  if (tid < BM) {
    int gi = m0 + tid;
    if (gi < cnt) { rowPid[tid] = pairIdx[e * CAP + gi]; rowW[tid] = pairWgt[e * CAP + gi]; }
    else          { rowPid[tid] = -1;                    rowW[tid] = 0.f; }
  }
  const float* W2e = W2 + (size_t)e * NF * DIM;
  f32x4 zero = {0.f, 0.f, 0.f, 0.f};
  f32x4 acc[2][4];
  #pragma unroll
  for (int mi = 0; mi < 2; ++mi)
    #pragma unroll
    for (int ni = 0; ni < 4; ++ni) acc[mi][ni] = zero;
  int lane = tid & 63, wid = tid >> 6;
  int wm = (wid >> 1) * 32, wn = (wid & 1) * 64;

  for (int kt = 0; kt < NF; kt += BK) {
    __syncthreads();
    #pragma unroll
    for (int it = 0; it < 2; ++it) {
      int row = it * 64 + (tid >> 3);
      int c8  = tid & 7;
      int pid = rowPid[row];
      int pr  = (pid >= 0) ? pid : 0;
      uint4 v = *(const uint4*)(hbuf + (size_t)pr * NF + kt + c8 * 8);
      *(uint4*)(&As[row * BK + ((c8 * 8) ^ swzo(row))]) = v;
    }
    #pragma unroll
    for (int it = 0; it < 4; ++it) {
      int fk = it * 16 + (tid >> 5);
      int dq = tid & 31;
      float4 v = *(const float4*)(W2e + (size_t)(kt + fk) * DIM + n0 + dq * 4);
      const float* p = (const float*)&v;
      #pragma unroll
      for (int i = 0; i < 4; ++i) {
        int dc = dq * 4 + i;
        Bs[dc * BK + (fk ^ swzo(dc))] = f2bf(p[i]);
      }
    }
    __syncthreads();
    #pragma unroll
    for (int ks = 0; ks < 2; ++ks) {
      int kb = ks * 32 + ((lane >> 4) << 3);
      bf16x8 af[2];
      #pragma unroll
      for (int mi = 0; mi < 2; ++mi) {
        int row = wm + mi * 16 + (lane & 15);
        af[mi] = *(const bf16x8*)(&As[row * BK + (kb ^ swzo(row))]);
      }
      #pragma unroll
      for (int ni = 0; ni < 4; ++ni) {
        int dc = wn + ni * 16 + (lane & 15);
        bf16x8 b = *(const bf16x8*)(&Bs[dc * BK + (kb ^ swzo(dc))]);
        #pragma unroll
        for (int mi = 0; mi < 2; ++mi)
          acc[mi][ni] = __builtin_amdgcn_mfma_f32_16x16x32_bf16(af[mi], b, acc[mi][ni], 0, 0, 0);
      }
    }
  }
  #pragma unroll
  for (int mi = 0; mi < 2; ++mi) {
    #pragma unroll
    for (int r = 0; r < 4; ++r) {
      int row = wm + mi * 16 + ((lane >> 4) << 2) + r;
      int pid = rowPid[row];
      if (pid < 0) continue;
      float w = rowW[row];
      float* op = out + (size_t)(pid >> 1) * DIM + n0 + wn + (lane & 15);
      #pragma unroll
      for (int ni = 0; ni < 4; ++ni)
        atomicAdd(op + ni * 16, w * acc[mi][ni][r]);
    }
  }
}

extern "C" void kernel_launch(void* const* d_in, const int* in_sizes, int n_in,
                              void* d_out, int out_size, void* d_ws, size_t ws_size,
                              hipStream_t stream)
{
  const float* x  = (const float*)d_in[0];
  const float* Wg = (const float*)d_in[1];
  const float* W1 = (const float*)d_in[2];
  const float* W2 = (const float*)d_in[3];
  const float* W3 = (const float*)d_in[4];
  float* out = (float*)d_out;
  char*  ws  = (char*)d_ws;
  int*   pairCnt = (int*)ws;
  float* auxSum  = (float*)(ws + 64);
  int*   pairIdx = (int*)(ws + 4096);
  float* pairWgt = (float*)(ws + 262144);
  // fast-path layout (from 1 MiB): xbf 8M, hbuf 64M, W13T 128M, W2T 64M
  unsigned short* xbf  = (unsigned short*)(ws + ((size_t)1 << 20));
  unsigned short* hbuf = (unsigned short*)(ws + ((size_t)9 << 20));
  unsigned short* W13T = (unsigned short*)(ws + ((size_t)73 << 20));
  unsigned short* W2T  = (unsigned short*)(ws + ((size_t)201 << 20));
  const size_t WS_NEED = (size_t)265 << 20;

  hipMemsetAsync(ws, 0, 128, stream);
  hipMemsetAsync(d_out, 0, (size_t)out_size * sizeof(float), stream);
  moe_route<<<TOKS / 4, 256, 0, stream>>>(x, Wg, pairCnt, pairIdx, pairWgt, auxSum);
  moe_aux_final<<<1, 1, 0, stream>>>(auxSum, out + (out_size - 1));

  if (ws_size >= WS_NEED) {
    cvt_x<<<TOKS * DIM / (256 * 16), 256, 0, stream>>>(x, xbf);
    cvt_w13<<<dim3(DIM / 64, NF / 64, NEXP), 256, 0, stream>>>(W1, W3, W13T);
    cvt_transpose<<<dim3(NF / 64, DIM / 64, NEXP), 256, 0, stream>>>(W2, W2T, NF, DIM);
    moe_ffn1_i<<<(TOKS / BM) * (2 * NF / BN) * NEXP, 512, 0, stream>>>(xbf, W13T, pairCnt, pairIdx, hbuf);
    moe_ffn2_g<<<(TOKS / BM) * (DIM / BN) * NEXP, 512, 0, stream>>>(hbuf, W2T, pairCnt, pairIdx, pairWgt, out);
  } else {
    moe_ffn1<<<dim3(TOKS / BM, NF / BN, NEXP), 512, 0, stream>>>(x, W1, W3, pairCnt, pairIdx, hbuf);
    moe_ffn2<<<dim3(TOKS / BM, DIM / BN, NEXP), 512, 0, stream>>>(hbuf, W2, pairCnt, pairIdx, pairWgt, out);
  }
}